// Round 10
// baseline (91.221 us; speedup 1.0000x reference)
//
#include <hip/hip_runtime.h>
#include <math.h>

// Encoder: x(B,T,N) -> LSTM gates (f-gate dead: c_prev=0) -> query=[h,c]
// -> s2 = query@w2 -> e[n] = sum_k tanh(x[n]*w1[k]+w1b[k]+s2[k])*v[k]
// -> softmax over n -> out = x*alpha.   B=64 T=128 N=U=T=128.
//
// r9 falsified trans-rate theory; r7 counters + arithmetic say enc is a
// SERIAL SUM of barrier-separated phases each using a different pipe
// (GEMM: MFMA+VMEM, spline: VALU+trans, epilogue: LDS+VALU) with only
// 1-2 blocks/CU -> no cross-block pipe overlap. r10: 16-row blocks at
// 128 thr (2 waves), grid 512, LDS 27 KB, launch_bounds(128,3) ->
// 5-6 independent blocks/CU overlap their phases on each CU's pipes.
// v_bias omitted: softmax is shift-invariant.
//
// Verified gfx950 16x16x32 bf16 layouts (m89/m91/m120):
//   A-frag: lane l holds A[m=l&15][k=(l>>4)*8+j], j=0..7
//   B-frag: lane l holds B[k=(l>>4)*8+j][n=l&15]
//   C/D   : reg r  is  C[row=(l>>4)*4+r][col=l&15]

typedef __attribute__((ext_vector_type(8))) short short8;
typedef __attribute__((ext_vector_type(4))) float f32x4;

#define BT 8192
#define NF 128
#define XP 132          /* xs/c2 row pad */
#define NNODE 12        /* spline nodes per row */
#define NSPAN 9.f       /* intervals spanning [mn,mx]: nodes 1..10 */
#define K_C     2.8853900817779268f   /* 2*log2(e) */
#define K_LOG2E 1.4426950408889634f

__device__ __forceinline__ float fast_rcp(float x)  { return __builtin_amdgcn_rcpf(x); }
__device__ __forceinline__ float fast_exp2(float x) { return __builtin_amdgcn_exp2f(x); }

__device__ __forceinline__ float tanh_nc(float tC) {
    return fmaf(-2.f, fast_rcp(1.f + fast_exp2(tC)), 1.f);
}
__device__ __forceinline__ float tanh_fast(float t) { return tanh_nc(t * K_C); }
__device__ __forceinline__ float sig_fast(float z) {
    return fast_rcp(1.f + fast_exp2(-K_LOG2E * z));
}
__device__ __forceinline__ unsigned short f2bf(float f) {
    unsigned u = __float_as_uint(f);
    return (unsigned short)((u + 0x7fffu + ((u >> 16) & 1u)) >> 16);
}

// ---------------- prep: weights -> bf16 frag order in ws (unchanged) ----
// ws (ushort units): B1f[96 frag-sets][512] then B2f[64][512].
__global__ __launch_bounds__(64) void prep(const float* __restrict__ Wl,
                                           const float* __restrict__ w2,
                                           unsigned short* __restrict__ wsB) {
    const int lane = threadIdx.x;
    const int n16 = lane & 15, q = lane >> 4;
    const int b = blockIdx.x;
    if (b < 96) {
        const int nt = b >> 2, kk = b & 3;
        const int g = nt >> 3, jt = nt & 7;
        const int goff = (g == 0) ? 0 : (g == 1 ? 256 : 384);
        const int col = goff + jt * 16 + n16;
        unsigned short* d = wsB + b * 512 + lane * 8;
        #pragma unroll
        for (int j = 0; j < 8; j++)
            d[j] = f2bf(Wl[(kk * 32 + q * 8 + j) * 512 + col]);
    } else {
        const int fs = b - 96;
        const int nt2 = fs >> 3, kk2 = fs & 7;
        const int col = nt2 * 16 + n16;
        unsigned short* d = wsB + 49152 + fs * 512 + lane * 8;
        #pragma unroll
        for (int j = 0; j < 8; j++)
            d[j] = f2bf(w2[(kk2 * 32 + q * 8 + j) * 128 + col]);
    }
}

// ---------------- enc: fused kernel, 5-6 blocks/CU for phase overlap ----
// grid 512, block 128 (2 waves). Wave w owns u16-tiles {4w..4w+3} in
// both GEMMs (tile-by-tile, transient B-frags -> low VGPR).
__global__ __launch_bounds__(128, 3) void enc(
    const float* __restrict__ x,  const unsigned short* __restrict__ wsB,
    const float* __restrict__ bl, const float* __restrict__ b2,
    const float* __restrict__ b1, const float* __restrict__ w1,
    const float* __restrict__ v,  float* __restrict__ out)
{
    __shared__ __align__(16) float xs[16][XP];        // 8.4 KB
    __shared__ unsigned short Qf[4096];               // 8 KB: query A-frags
    __shared__ __align__(16) float c2[16][XP];        // 8.4 KB
    __shared__ __align__(16) float w1Cs[NF], vs[NF];  // 1 KB
    __shared__ float Ftab[16][13];                    // 832 B
    __shared__ float rowMn[16], rowMx[16];

    const int t    = threadIdx.x;
    const int lane = t & 63, w = t >> 6;              // w in {0,1}
    const int n16  = lane & 15, q = lane >> 4;
    const int rowbase = blockIdx.x * 16;

    // stage xs: 4 coalesced float4/thread + row min/max (32 lanes/row)
    #pragma unroll
    for (int p = 0; p < 4; p++) {
        const int i   = t + p * 128;          // float4 index in [0,512)
        const int row = i >> 5, col = (i & 31) * 4;
        const float4 a = *(const float4*)(x + (rowbase + row) * NF + col);
        *(float4*)&xs[row][col] = a;
        float mn = fminf(fminf(a.x, a.y), fminf(a.z, a.w));
        float mx = fmaxf(fmaxf(a.x, a.y), fmaxf(a.z, a.w));
        #pragma unroll
        for (int off = 1; off < 32; off <<= 1) {
            mn = fminf(mn, __shfl_xor(mn, off, 32));
            mx = fmaxf(mx, __shfl_xor(mx, off, 32));
        }
        if ((t & 31) == 0) { rowMn[row] = mn; rowMx[row] = mx; }
    }
    w1Cs[t] = w1[t] * K_C;                    // 128 threads == NF exactly
    vs[t]   = v[t];
    __syncthreads();   // barrier 0: xs, rowMn/Mx, w1Cs, vs ready

    // A-frags from LDS xs (f32 -> bf16 in-register), all 16 rows
    short8 af[4];
    #pragma unroll
    for (int kk = 0; kk < 4; kk++) {
        const float4 v0 = *(const float4*)&xs[n16][kk * 32 + q * 8];
        const float4 v1 = *(const float4*)&xs[n16][kk * 32 + q * 8 + 4];
        short8 a;
        a[0] = f2bf(v0.x); a[1] = f2bf(v0.y); a[2] = f2bf(v0.z); a[3] = f2bf(v0.w);
        a[4] = f2bf(v1.x); a[5] = f2bf(v1.y); a[6] = f2bf(v1.z); a[7] = f2bf(v1.w);
        af[kk] = a;
    }

    // GEMM1 + gates, tile-by-tile (transient B-frags keep VGPR low)
    const short8* B1g = (const short8*)wsB;
    #pragma unroll
    for (int j4 = 0; j4 < 4; j4++) {
        const int jt = w * 4 + j4;
        short8 bf[3][4];
        #pragma unroll
        for (int g = 0; g < 3; g++)
            #pragma unroll
            for (int kk = 0; kk < 4; kk++)
                bf[g][kk] = B1g[((g * 8 + jt) * 4 + kk) * 64 + lane];
        f32x4 acc[3];
        #pragma unroll
        for (int g = 0; g < 3; g++) acc[g] = (f32x4)(0.f);
        #pragma unroll
        for (int kk = 0; kk < 4; kk++)
            #pragma unroll
            for (int g = 0; g < 3; g++)
                acc[g] = __builtin_amdgcn_mfma_f32_16x16x32_bf16(
                    af[kk], bf[g][kk], acc[g], 0, 0, 0);

        // gates -> query bf16 into Qf in GEMM2 A-frag order (K=256: h,c)
        const int u = jt * 16 + n16;
        const float bi = bl[u], bg = bl[256 + u], bo = bl[384 + u];
        const int kqc = NF + u;
        const int baseh = (u >> 5) * 512 + ((u & 31) >> 3) * 128 + q * 32 + (u & 7);
        const int basec = (kqc >> 5) * 512 + ((kqc & 31) >> 3) * 128 + q * 32 + (kqc & 7);
        #pragma unroll
        for (int r = 0; r < 4; r++) {
            const float cc = sig_fast(acc[0][r] + bi) * tanh_fast(acc[1][r] + bg);
            const float hh = sig_fast(acc[2][r] + bo) * tanh_fast(cc);
            Qf[baseh + r * 8] = f2bf(hh);
            Qf[basec + r * 8] = f2bf(cc);
        }
    }
    __syncthreads();   // barrier A: Qf ready

    // GEMM2: A-frags (query) loaded once, 4 tiles/wave
    {
        short8 a2[8];
        #pragma unroll
        for (int kk2 = 0; kk2 < 8; kk2++)
            a2[kk2] = *(const short8*)&Qf[kk2 * 512 + lane * 8];
        const short8* B2g = (const short8*)(wsB + 49152);
        #pragma unroll
        for (int j4 = 0; j4 < 4; j4++) {
            const int nt2 = w * 4 + j4;
            short8 b2f[8];
            #pragma unroll
            for (int kk2 = 0; kk2 < 8; kk2++)
                b2f[kk2] = B2g[(nt2 * 8 + kk2) * 64 + lane];
            f32x4 acc2 = (f32x4)(0.f);
            #pragma unroll
            for (int kk2 = 0; kk2 < 8; kk2++)
                acc2 = __builtin_amdgcn_mfma_f32_16x16x32_bf16(a2[kk2], b2f[kk2], acc2, 0, 0, 0);
            const int u2 = nt2 * 16 + n16;
            const float bias2 = (b2[u2] + b1[u2]) * K_C;   // pre-scaled for spline
            #pragma unroll
            for (int r = 0; r < 4; r++)
                c2[q * 4 + r][u2] = fmaf(acc2[r], K_C, bias2);
        }
    }
    __syncthreads();   // barrier B: c2 ready

    // Node eval, incremental-exp2. Thread = (row = t>>3, ks = t&7);
    // each handles k-octets {ks, ks+8} (16 k) with 8 E-chains per pass:
    // E_0 = exp2(aC*xi0+cC), D = exp2(aC*h); per node: G += v*rcp(1+E),
    // E *= D. F_m = sum_v - 2*G_m. Width-8 butterfly (rows of 8 lanes).
    {
        const int row = t >> 3, ks = t & 7;
        const float mn  = rowMn[row];
        const float h   = (rowMx[row] - mn) * (1.f / NSPAN);
        const float xi0 = mn - h;             // node m=0
        float G[NNODE];
        #pragma unroll
        for (int m = 0; m < NNODE; m++) G[m] = 0.f;
        float sv = 0.f;
        #pragma unroll
        for (int half = 0; half < 2; half++) {
            const int k0 = (ks + half * 8) * 8;
            const float4 wa = *(const float4*)&w1Cs[k0];
            const float4 wb = *(const float4*)&w1Cs[k0 + 4];
            const float4 ca = *(const float4*)&c2[row][k0];
            const float4 cb = *(const float4*)&c2[row][k0 + 4];
            const float4 va = *(const float4*)&vs[k0];
            const float4 vb = *(const float4*)&vs[k0 + 4];
            float aC[8] = {wa.x, wa.y, wa.z, wa.w, wb.x, wb.y, wb.z, wb.w};
            float cC[8] = {ca.x, ca.y, ca.z, ca.w, cb.x, cb.y, cb.z, cb.w};
            float vv[8] = {va.x, va.y, va.z, va.w, vb.x, vb.y, vb.z, vb.w};
            float E[8], D[8];
            #pragma unroll
            for (int j = 0; j < 8; j++) {
                E[j] = fast_exp2(fmaf(aC[j], xi0, cC[j]));
                D[j] = fast_exp2(aC[j] * h);
                sv  += vv[j];
            }
            #pragma unroll
            for (int m = 0; m < NNODE; m++) {
                float g = 0.f;
                #pragma unroll
                for (int j = 0; j < 8; j++) {
                    g = fmaf(vv[j], fast_rcp(1.f + E[j]), g);
                    E[j] *= D[j];
                }
                G[m] += g;
            }
        }
        #pragma unroll
        for (int off = 1; off < 8; off <<= 1) {
            sv += __shfl_xor(sv, off, 8);
            #pragma unroll
            for (int m = 0; m < NNODE; m++) G[m] += __shfl_xor(G[m], off, 8);
        }
        Ftab[row][ks] = fmaf(-2.f, G[ks], sv);
        if (ks < 4) Ftab[row][8 + ks] = fmaf(-2.f, G[8 + ks], sv);
    }
    __syncthreads();   // barrier C: Ftab ready

    // Interp + softmax + store: 8 threads/row, 16 consecutive n each.
    {
        const int row = t >> 3;
        const int n0  = (t & 7) * 16;
        const float mn   = rowMn[row];
        const float span = rowMx[row] - mn;
        const float invh = span > 1e-12f ? NSPAN / span : 0.f;
        float xv[16], e16[16];
        #pragma unroll
        for (int p = 0; p < 4; p++)
            *(float4*)&xv[p * 4] = *(const float4*)&xs[row][n0 + p * 4];
        #pragma unroll
        for (int i = 0; i < 16; i++) {
            const float sN = fmaf(xv[i] - mn, invh, 1.0f);   // in [1, 10]
            int ii = (int)sN;
            ii = ii < 1 ? 1 : (ii > NNODE - 3 ? NNODE - 3 : ii);
            const float f  = sN - (float)ii;
            const float F0 = Ftab[row][ii - 1], F1 = Ftab[row][ii];
            const float F2 = Ftab[row][ii + 1], F3 = Ftab[row][ii + 2];
            e16[i] = F1 + 0.5f * f * ((F2 - F0)
                   + f * ((2.f * F0 - 5.f * F1 + 4.f * F2 - F3)
                   + f * (3.f * (F1 - F2) + F3 - F0)));
        }
        float mval = e16[0];
        #pragma unroll
        for (int i = 1; i < 16; i++) mval = fmaxf(mval, e16[i]);
        #pragma unroll
        for (int off = 1; off < 8; off <<= 1)
            mval = fmaxf(mval, __shfl_xor(mval, off, 8));
        float ssum = 0.f;
        #pragma unroll
        for (int i = 0; i < 16; i++) {
            e16[i] = fast_exp2(K_LOG2E * (e16[i] - mval));
            ssum += e16[i];
        }
        #pragma unroll
        for (int off = 1; off < 8; off <<= 1)
            ssum += __shfl_xor(ssum, off, 8);
        const float rs = fast_rcp(ssum);
        float* op = out + (rowbase + row) * NF + n0;
        #pragma unroll
        for (int p = 0; p < 4; p++) {
            float4 o;
            o.x = xv[p * 4 + 0] * e16[p * 4 + 0] * rs;
            o.y = xv[p * 4 + 1] * e16[p * 4 + 1] * rs;
            o.z = xv[p * 4 + 2] * e16[p * 4 + 2] * rs;
            o.w = xv[p * 4 + 3] * e16[p * 4 + 3] * rs;
            *(float4*)(op + p * 4) = o;
        }
    }
}

extern "C" void kernel_launch(void* const* d_in, const int* in_sizes, int n_in,
                              void* d_out, int out_size, void* d_ws, size_t ws_size,
                              hipStream_t stream) {
    const float* x  = (const float*)d_in[0];
    // d_in[1]=hidden_state, d_in[2]=cell_state: ignored by reference semantics
    const float* Wl = (const float*)d_in[3];   // (128, 512)
    const float* bl = (const float*)d_in[4];   // (512,)
    const float* w1 = (const float*)d_in[5];   // (1, 128)
    const float* b1 = (const float*)d_in[6];   // (128,)
    const float* w2 = (const float*)d_in[7];   // (256, 128)
    const float* b2 = (const float*)d_in[8];   // (128,)
    const float* v  = (const float*)d_in[9];   // (128, 1)
    // d_in[10]=v_bias: softmax-invariant, omitted. d_in[11]=n: unused.
    float* out = (float*)d_out;
    unsigned short* wsB = (unsigned short*)d_ws;   // 160 KB bf16 frag weights

    prep<<<160, 64, 0, stream>>>(Wl, w2, wsB);
    enc<<<BT / 16, 128, 0, stream>>>(x, wsB, bl, b2, b1, w1, v, out);
}

// Round 11
// 86.029 us; speedup vs baseline: 1.0603x; 1.0603x over previous
//
#include <hip/hip_runtime.h>
#include <math.h>

// Encoder: x(B,T,N) -> LSTM gates (f-gate dead: c_prev=0) -> query=[h,c]
// -> s2 = query@w2 -> e[n] = sum_k tanh(x[n]*w1[k]+w1b[k]+s2[k])*v[k]
// -> softmax over n -> out = x*alpha.   B=64 T=128 N=U=T=128.
//
// FINAL STRUCTURE (r9 = session best, 86.6 us; r10's small-block variant
// regressed and is reverted). Six structural variants (r5/r6/r8/r9/r10)
// all land 86.5-91.2 us: enc is pinned at ~17 us, harness fixed cost ~69 us
// (268 MB d_ws 0xAA poison = 41 us + restores/gaps). Only delta vs r9:
// NNODE 12 -> 10 (node count is error-invisible; absmax identical at
// 32/16/12 nodes, bf16-GEMM rounding dominates).
// v_bias omitted: softmax is shift-invariant.
//
// Verified gfx950 16x16x32 bf16 layouts (m89/m91/m120):
//   A-frag: lane l holds A[m=l&15][k=(l>>4)*8+j], j=0..7
//   B-frag: lane l holds B[k=(l>>4)*8+j][n=l&15]
//   C/D   : reg r  is  C[row=(l>>4)*4+r][col=l&15]

typedef __attribute__((ext_vector_type(8))) short short8;
typedef __attribute__((ext_vector_type(4))) float f32x4;

#define BT 8192
#define NF 128
#define XP 132          /* xs/c2 row pad */
#define NNODE 10        /* spline nodes per row */
#define NSPAN 7.f       /* intervals spanning [mn,mx]: nodes 1..8 */
#define K_C     2.8853900817779268f   /* 2*log2(e) */
#define K_LOG2E 1.4426950408889634f

__device__ __forceinline__ float fast_rcp(float x)  { return __builtin_amdgcn_rcpf(x); }
__device__ __forceinline__ float fast_exp2(float x) { return __builtin_amdgcn_exp2f(x); }

__device__ __forceinline__ float tanh_nc(float tC) {
    return fmaf(-2.f, fast_rcp(1.f + fast_exp2(tC)), 1.f);
}
__device__ __forceinline__ float tanh_fast(float t) { return tanh_nc(t * K_C); }
__device__ __forceinline__ float sig_fast(float z) {
    return fast_rcp(1.f + fast_exp2(-K_LOG2E * z));
}
__device__ __forceinline__ unsigned short f2bf(float f) {
    unsigned u = __float_as_uint(f);
    return (unsigned short)((u + 0x7fffu + ((u >> 16) & 1u)) >> 16);
}

// ---------------- prep: weights -> bf16 frag order in ws ----------------
// ws (ushort units): B1f[96 frag-sets][512] then B2f[64][512].
__global__ __launch_bounds__(64) void prep(const float* __restrict__ Wl,
                                           const float* __restrict__ w2,
                                           unsigned short* __restrict__ wsB) {
    const int lane = threadIdx.x;
    const int n16 = lane & 15, q = lane >> 4;
    const int b = blockIdx.x;
    if (b < 96) {
        const int nt = b >> 2, kk = b & 3;
        const int g = nt >> 3, jt = nt & 7;
        const int goff = (g == 0) ? 0 : (g == 1 ? 256 : 384);
        const int col = goff + jt * 16 + n16;
        unsigned short* d = wsB + b * 512 + lane * 8;
        #pragma unroll
        for (int j = 0; j < 8; j++)
            d[j] = f2bf(Wl[(kk * 32 + q * 8 + j) * 512 + col]);
    } else {
        const int fs = b - 96;
        const int nt2 = fs >> 3, kk2 = fs & 7;
        const int col = nt2 * 16 + n16;
        unsigned short* d = wsB + 49152 + fs * 512 + lane * 8;
        #pragma unroll
        for (int j = 0; j < 8; j++)
            d[j] = f2bf(w2[(kk2 * 32 + q * 8 + j) * 128 + col]);
    }
}

// ---------------- enc: weight-stationary fused kernel (r9) ----------------
// grid 256, block 512 (8 waves). Wave w owns u16-tile w; block owns
// 32 rows = 2 MFMA m-tiles (chunks).
__global__ __launch_bounds__(512, 2) void enc(
    const float* __restrict__ x,  const unsigned short* __restrict__ wsB,
    const float* __restrict__ bl, const float* __restrict__ b2,
    const float* __restrict__ b1, const float* __restrict__ w1,
    const float* __restrict__ v,  float* __restrict__ out)
{
    __shared__ __align__(16) float xs[32][XP];        // 16.5 KB
    __shared__ unsigned short Qf[2][4096];            // 16 KB: query A-frags
    __shared__ __align__(16) float c2[32][XP];        // 16.5 KB
    __shared__ __align__(16) float w1Cs[NF], vs[NF];  // 1 KB
    __shared__ float Ftab[32][NNODE + 1];             // 1.4 KB
    __shared__ float rowMn[32], rowMx[32];

    const int t    = threadIdx.x;
    const int lane = t & 63, w = t >> 6;
    const int n16  = lane & 15, q = lane >> 4;
    const int rowbase = blockIdx.x * 32;

    // B1-frags: issue EARLY (latency hidden under x staging), keep resident
    const short8* B1g = (const short8*)wsB;
    short8 b1f[3][4];
    #pragma unroll
    for (int g = 0; g < 3; g++)
        #pragma unroll
        for (int kk = 0; kk < 4; kk++)
            b1f[g][kk] = B1g[((g * 8 + w) * 4 + kk) * 64 + lane];

    // stage xs: fully-coalesced float4s + row min/max (32 lanes per row)
    #pragma unroll
    for (int p = 0; p < 2; p++) {
        const int i   = t + p * 512;          // float4 index in [0,1024)
        const int row = i >> 5, col = (i & 31) * 4;
        const float4 a = *(const float4*)(x + (rowbase + row) * NF + col);
        *(float4*)&xs[row][col] = a;
        float mn = fminf(fminf(a.x, a.y), fminf(a.z, a.w));
        float mx = fmaxf(fmaxf(a.x, a.y), fmaxf(a.z, a.w));
        #pragma unroll
        for (int off = 1; off < 32; off <<= 1) {
            mn = fminf(mn, __shfl_xor(mn, off, 32));
            mx = fmaxf(mx, __shfl_xor(mx, off, 32));
        }
        if ((t & 31) == 0) { rowMn[row] = mn; rowMx[row] = mx; }
    }
    if (t < NF) { w1Cs[t] = w1[t] * K_C; vs[t] = v[t]; }
    __syncthreads();   // barrier 0: xs, rowMn/Mx, w1Cs, vs ready

    // A-frags for both chunks from LDS (f32 -> bf16 in-register)
    short8 af[2][4];
    #pragma unroll
    for (int c = 0; c < 2; c++)
        #pragma unroll
        for (int kk = 0; kk < 4; kk++) {
            const float4 v0 = *(const float4*)&xs[c * 16 + n16][kk * 32 + q * 8];
            const float4 v1 = *(const float4*)&xs[c * 16 + n16][kk * 32 + q * 8 + 4];
            short8 a;
            a[0] = f2bf(v0.x); a[1] = f2bf(v0.y); a[2] = f2bf(v0.z); a[3] = f2bf(v0.w);
            a[4] = f2bf(v1.x); a[5] = f2bf(v1.y); a[6] = f2bf(v1.z); a[7] = f2bf(v1.w);
            af[c][kk] = a;
        }

    // GEMM1: both chunks reuse the register-resident B1-frags
    f32x4 acc[2][3];
    #pragma unroll
    for (int c = 0; c < 2; c++)
        #pragma unroll
        for (int g = 0; g < 3; g++) acc[c][g] = (f32x4)(0.f);
    #pragma unroll
    for (int kk = 0; kk < 4; kk++)
        #pragma unroll
        for (int c = 0; c < 2; c++)
            #pragma unroll
            for (int g = 0; g < 3; g++)
                acc[c][g] = __builtin_amdgcn_mfma_f32_16x16x32_bf16(
                    af[c][kk], b1f[g][kk], acc[c][g], 0, 0, 0);

    // Gates -> query bf16 into Qf[c] in GEMM2 A-frag order (K=256: h,c).
    const int u = w * 16 + n16;
    {
        const float bi = bl[u], bg = bl[256 + u], bo = bl[384 + u];
        const int kqh = u, kqc = NF + u;
        const int baseh = (kqh >> 5) * 512 + ((kqh & 31) >> 3) * 128 + q * 32 + (kqh & 7);
        const int basec = (kqc >> 5) * 512 + ((kqc & 31) >> 3) * 128 + q * 32 + (kqc & 7);
        #pragma unroll
        for (int c = 0; c < 2; c++)
            #pragma unroll
            for (int r = 0; r < 4; r++) {
                const float cc = sig_fast(acc[c][0][r] + bi) * tanh_fast(acc[c][1][r] + bg);
                const float hh = sig_fast(acc[c][2][r] + bo) * tanh_fast(cc);
                Qf[c][baseh + r * 8] = f2bf(hh);
                Qf[c][basec + r * 8] = f2bf(cc);
            }
    }
    __syncthreads();   // barrier A: Qf ready

    // GEMM2: B2-frags loaded once, reused for both chunks
    {
        const short8* B2g = (const short8*)(wsB + 49152);
        short8 b2f[8];
        #pragma unroll
        for (int kk2 = 0; kk2 < 8; kk2++)
            b2f[kk2] = B2g[(w * 8 + kk2) * 64 + lane];
        const float bias2 = (b2[u] + b1[u]) * K_C;   // pre-scaled for spline
        #pragma unroll
        for (int c = 0; c < 2; c++) {
            short8 a2[8];
            #pragma unroll
            for (int kk2 = 0; kk2 < 8; kk2++)
                a2[kk2] = *(const short8*)&Qf[c][kk2 * 512 + lane * 8];
            f32x4 acc2 = (f32x4)(0.f);
            #pragma unroll
            for (int kk2 = 0; kk2 < 8; kk2++)
                acc2 = __builtin_amdgcn_mfma_f32_16x16x32_bf16(a2[kk2], b2f[kk2], acc2, 0, 0, 0);
            #pragma unroll
            for (int r = 0; r < 4; r++)
                c2[c * 16 + q * 4 + r][u] = fmaf(acc2[r], K_C, bias2);
        }
    }
    __syncthreads();   // barrier B: c2 ready

    // Node eval, incremental-exp2 form. Thread = (row = t>>4, k-octet
    // ks = t&15). Per k: E_0 = exp2(aC*xi0 + cC), D = exp2(aC*h);
    // per node m: G_m += v_k * rcp(1 + E), E *= D  (rcp is the only trans).
    // F_m = sum_v - 2*G_m. 8 independent E-chains -> rcp ILP. exp2
    // saturation (inf/0) yields correct tanh limits (+1/-1).
    {
        const int row = t >> 4;
        const int ks  = t & 15;
        const int k0  = ks * 8;
        const float mn = rowMn[row];
        const float h  = (rowMx[row] - mn) * (1.f / NSPAN);
        const float xi0 = mn - h;            // node m=0
        const float4 wa = *(const float4*)&w1Cs[k0];
        const float4 wb = *(const float4*)&w1Cs[k0 + 4];
        const float4 ca = *(const float4*)&c2[row][k0];
        const float4 cb = *(const float4*)&c2[row][k0 + 4];
        const float4 va = *(const float4*)&vs[k0];
        const float4 vb = *(const float4*)&vs[k0 + 4];
        float aC[8] = {wa.x, wa.y, wa.z, wa.w, wb.x, wb.y, wb.z, wb.w};
        float cC[8] = {ca.x, ca.y, ca.z, ca.w, cb.x, cb.y, cb.z, cb.w};
        float vv[8] = {va.x, va.y, va.z, va.w, vb.x, vb.y, vb.z, vb.w};
        float E[8], D[8], sv = 0.f;
        #pragma unroll
        for (int j = 0; j < 8; j++) {
            E[j] = fast_exp2(fmaf(aC[j], xi0, cC[j]));
            D[j] = fast_exp2(aC[j] * h);
            sv  += vv[j];
        }
        float G[NNODE];
        #pragma unroll
        for (int m = 0; m < NNODE; m++) {
            float g = 0.f;
            #pragma unroll
            for (int j = 0; j < 8; j++) {
                g = fmaf(vv[j], fast_rcp(1.f + E[j]), g);
                E[j] *= D[j];
            }
            G[m] = g;
        }
        // butterfly over the 16 k-octet lanes (width-16 groups in-wave)
        #pragma unroll
        for (int off = 1; off < 16; off <<= 1) {
            sv += __shfl_xor(sv, off, 16);
            #pragma unroll
            for (int m = 0; m < NNODE; m++) G[m] += __shfl_xor(G[m], off, 16);
        }
        #pragma unroll
        for (int m = 0; m < NNODE; m++)
            if (ks == m) Ftab[row][m] = fmaf(-2.f, G[m], sv);
    }
    __syncthreads();   // barrier C: Ftab ready

    // Interp + softmax + store: 16 threads/row, 8 consecutive n each.
    {
        const int row = t >> 4;
        const int n0  = (t & 15) * 8;
        const float mn   = rowMn[row];
        const float span = rowMx[row] - mn;
        const float invh = span > 1e-12f ? NSPAN / span : 0.f;
        float xv[8], e8[8];
        *(float4*)&xv[0] = *(const float4*)&xs[row][n0];
        *(float4*)&xv[4] = *(const float4*)&xs[row][n0 + 4];
        #pragma unroll
        for (int i = 0; i < 8; i++) {
            const float sN = fmaf(xv[i] - mn, invh, 1.0f);   // in [1, 8]
            int ii = (int)sN;
            ii = ii < 1 ? 1 : (ii > NNODE - 3 ? NNODE - 3 : ii);
            const float f  = sN - (float)ii;
            const float F0 = Ftab[row][ii - 1], F1 = Ftab[row][ii];
            const float F2 = Ftab[row][ii + 1], F3 = Ftab[row][ii + 2];
            e8[i] = F1 + 0.5f * f * ((F2 - F0)
                  + f * ((2.f * F0 - 5.f * F1 + 4.f * F2 - F3)
                  + f * (3.f * (F1 - F2) + F3 - F0)));
        }
        float mval = e8[0];
        #pragma unroll
        for (int i = 1; i < 8; i++) mval = fmaxf(mval, e8[i]);
        #pragma unroll
        for (int off = 1; off < 16; off <<= 1)
            mval = fmaxf(mval, __shfl_xor(mval, off, 16));
        float ssum = 0.f;
        #pragma unroll
        for (int i = 0; i < 8; i++) {
            e8[i] = fast_exp2(K_LOG2E * (e8[i] - mval));
            ssum += e8[i];
        }
        #pragma unroll
        for (int off = 1; off < 16; off <<= 1)
            ssum += __shfl_xor(ssum, off, 16);
        const float rs = fast_rcp(ssum);
        float4 o0, o1;
        o0.x = xv[0] * e8[0] * rs; o0.y = xv[1] * e8[1] * rs;
        o0.z = xv[2] * e8[2] * rs; o0.w = xv[3] * e8[3] * rs;
        o1.x = xv[4] * e8[4] * rs; o1.y = xv[5] * e8[5] * rs;
        o1.z = xv[6] * e8[6] * rs; o1.w = xv[7] * e8[7] * rs;
        float* op = out + (rowbase + row) * NF + n0;
        *(float4*)op       = o0;
        *(float4*)(op + 4) = o1;
    }
}

extern "C" void kernel_launch(void* const* d_in, const int* in_sizes, int n_in,
                              void* d_out, int out_size, void* d_ws, size_t ws_size,
                              hipStream_t stream) {
    const float* x  = (const float*)d_in[0];
    // d_in[1]=hidden_state, d_in[2]=cell_state: ignored by reference semantics
    const float* Wl = (const float*)d_in[3];   // (128, 512)
    const float* bl = (const float*)d_in[4];   // (512,)
    const float* w1 = (const float*)d_in[5];   // (1, 128)
    const float* b1 = (const float*)d_in[6];   // (128,)
    const float* w2 = (const float*)d_in[7];   // (256, 128)
    const float* b2 = (const float*)d_in[8];   // (128,)
    const float* v  = (const float*)d_in[9];   // (128, 1)
    // d_in[10]=v_bias: softmax-invariant, omitted. d_in[11]=n: unused.
    float* out = (float*)d_out;
    unsigned short* wsB = (unsigned short*)d_ws;   // 160 KB bf16 frag weights

    prep<<<160, 64, 0, stream>>>(Wl, w2, wsB);
    enc<<<BT / 32, 512, 0, stream>>>(x, wsB, bl, b2, b1, w1, v, out);
}